// Round 5
// baseline (1527.142 us; speedup 1.0000x reference)
//
#include <hip/hip_runtime.h>
#include <math.h>

#define T_LEN 16000
#define NTILE 250          // time tiles per batch row (16000/64)
#define TT 64              // time tile
#define NBLK 2000          // 8 * 250

static const int N_RES = 8 * 32 * T_LEN;   // 4,096,000 floats per residual buffer

typedef _Float16 half_t;
typedef __attribute__((ext_vector_type(8))) _Float16 halfx8;
typedef __attribute__((ext_vector_type(4))) _Float16 halfx4;
typedef __attribute__((ext_vector_type(16))) float f32x16;
typedef unsigned int uint32;
typedef unsigned short ushort16;

#define MFMA(a, b, c) __builtin_amdgcn_mfma_f32_32x32x16_f16((a), (b), (c), 0, 0, 0)

static __device__ inline uint32 packpair(float a, float b) {
  half_t ha = (half_t)a, hb = (half_t)b;
  return (uint32)__builtin_bit_cast(ushort16, ha) |
         ((uint32)__builtin_bit_cast(ushort16, hb) << 16);
}

// ---------------- weight repack ----------------
// WaG[l][o=0..127][k=0..127]: k<64: k=2c+s -> hi(Wd[l][o][c][s]); k>=64: lo*2048 of same
// WrG[l][o2=0..31][k=0..255]: kk=k&127 -> m via gT-perm; k<128 hi, k>=128 lo*2048
//   perm: mh=kk>>6; j2=kk&63; til=j2>>5; j=j2&31; lh=j>>4; rr=j&15; m=mh*64+til*32+(rr&3)+(rr>>2)*8+lh*4
// We1S[o][k=0..63]: k<32 hi We1[o][k], k>=32 lo*2048
// We2S[o][k=0..511]: k<256 hi We2[o][k], k>=256 lo*2048
__global__ __launch_bounds__(256) void repack_k(
    const float* __restrict__ Wd, const float* __restrict__ Wr,
    const float* __restrict__ Ws, const float* __restrict__ We1,
    const float* __restrict__ We2,
    half_t* __restrict__ WaG, half_t* __restrict__ WrG, float* __restrict__ WsT,
    half_t* __restrict__ We1S, half_t* __restrict__ We2S) {
  int i = blockIdx.x * 256 + threadIdx.x;
  if (i < 40 * 128 * 128) {
    int l = i >> 14, r = i & 16383, o = r >> 7, k = r & 127;
    int kk = k & 63, c = kk >> 1, s = kk & 1;
    float w = Wd[(((l * 128 + o) * 32 + c) << 1) + s];
    half_t w0 = (half_t)w;
    WaG[i] = (k < 64) ? w0 : (half_t)((w - (float)w0) * 2048.f);
  }
  if (i < 40 * 32 * 256) {
    int l = i >> 13, r = i & 8191, o2 = r >> 8, k = r & 255;
    int kk = k & 127;
    int mh = kk >> 6, j2 = kk & 63, til = j2 >> 5, j = j2 & 31, lh = j >> 4, rr = j & 15;
    int m = mh * 64 + til * 32 + (rr & 3) + ((rr >> 2) << 3) + lh * 4;
    float w = Wr[(l * 32 + o2) * 128 + m];
    half_t w0 = (half_t)w;
    WrG[i] = (k < 128) ? w0 : (half_t)((w - (float)w0) * 2048.f);
  }
  if (i < 8192) {
    int c = i >> 5, o = i & 31;
    WsT[i] = Ws[o * 256 + c];
  }
  if (i < 16384) {
    int o = i >> 6, k = i & 63;
    float w = We1[o * 32 + (k & 31)];
    half_t w0 = (half_t)w;
    We1S[i] = (k < 32) ? w0 : (half_t)((w - (float)w0) * 2048.f);
  }
  if (i < 131072) {
    int o = i >> 9, k = i & 511;
    float w = We2[o * 256 + (k & 255)];
    half_t w0 = (half_t)w;
    We2S[i] = (k < 256) ? w0 : (half_t)((w - (float)w0) * 2048.f);
  }
}

// ---------------- start 1x1 conv (f32): residual = W_start @ x ----------------
__global__ __launch_bounds__(256) void start_k(const float* __restrict__ x,
                                               const float* __restrict__ WsT,
                                               float* __restrict__ res) {
  __shared__ float xs[32][68];
  int b = blockIdx.x / NTILE;
  int t0 = (blockIdx.x % NTILE) * TT;
  int tid = threadIdx.x;
  int o = tid & 31, tg = (tid >> 5) * 8;
  int lr = tid >> 3, lt = (tid & 7) * 8;
  float acc[8];
#pragma unroll
  for (int j = 0; j < 8; ++j) acc[j] = 0.f;
  for (int cc = 0; cc < 8; ++cc) {
    __syncthreads();
    const float* xp = x + ((size_t)b * 256 + cc * 32 + lr) * T_LEN + t0 + lt;
    *(float4*)&xs[lr][lt]     = *(const float4*)xp;
    *(float4*)&xs[lr][lt + 4] = *(const float4*)(xp + 4);
    __syncthreads();
#pragma unroll 4
    for (int c = 0; c < 32; ++c) {
      float w = WsT[(cc * 32 + c) * 32 + o];
      const float* xr = &xs[c][tg];
#pragma unroll
      for (int j = 0; j < 8; ++j) acc[j] += w * xr[j];
    }
  }
  float* rp = res + ((size_t)b * 32 + o) * T_LEN + t0 + tg;
  *(float4*)rp       = make_float4(acc[0], acc[1], acc[2], acc[3]);
  *(float4*)(rp + 4) = make_float4(acc[4], acc[5], acc[6], acc[7]);
}

// ---------------- fused WaveNet layer: 3 blocks/CU, 1 tile/block ----------------
// LDS map (bytes):
//   [0,     17408)  zT  64 rows x 272B (K-interleaved pairs, XOR-swizzled) | skb overlay (2x32x68 f32)
//   [17408, 51200)  gT  64 rows x 528B (K=256 halves + pad, gT-perm cols)
__global__ __launch_bounds__(256, 3) void layer_k(const float* __restrict__ resIn,
                                                  float* __restrict__ resOut,
                                                  const half_t* __restrict__ WaL,
                                                  const half_t* __restrict__ WrL, int d) {
  __shared__ __align__(16) char sm[51200];
  const int ZT_OFF = 0, GT_OFF = 17408, SKB_OFF = 0;
  int tid = threadIdx.x;
  int wave = tid >> 6, lane = tid & 63;
  int l31 = lane & 31, lhi = lane >> 5;
  int mh = wave & 1, nh = wave >> 1;   // GEMM1 roles; GEMM2: colt2 = mh, kh = nh

  int b = blockIdx.x / NTILE;
  int t0 = (blockIdx.x % NTILE) * TT;

  // ---- stage zT (issue activation loads first; weight loads below overlap) ----
  {
    int c = tid >> 3, tw = (tid & 7) * 8;
    const float* rip = resIn + ((size_t)b * 32 + c) * T_LEN;
    float cv[8], pv[8];
    *(float4*)cv       = *(const float4*)(rip + t0 + tw);
    *(float4*)(cv + 4) = *(const float4*)(rip + t0 + tw + 4);
    int tp = t0 + tw - d;
    if (tp >= 0 && (d & 3) == 0) {
      *(float4*)pv       = *(const float4*)(rip + tp);
      *(float4*)(pv + 4) = *(const float4*)(rip + tp + 4);
    } else {
#pragma unroll
      for (int j = 0; j < 8; ++j) {
        int q = tp + j;
        pv[j] = (q >= 0) ? rip[q] : 0.f;
      }
    }
#pragma unroll
    for (int j = 0; j < 8; ++j) {
      int t = tw + j;
      int sw = ((t >> 3) & 3) << 5;
      char* zrow = sm + ZT_OFF + t * 272;
      half_t p0 = (half_t)pv[j];
      half_t c0 = (half_t)cv[j];
      float pl = (pv[j] - (float)p0) * 2048.f;
      float cl = (cv[j] - (float)c0) * 2048.f;
      *(uint32*)(zrow + ((c * 4) ^ sw))       = packpair(pv[j], cv[j]);
      *(uint32*)(zrow + ((c * 4 + 128) ^ sw)) = packpair(pl, cl);
    }
  }

  // ---- GEMM1 A-fragments from global (L2-hot), persistent (64 VGPR) ----
  halfx8 a1h0[4], a1l0[4], a1h1[4], a1l1[4];
  {
    const half_t* wa = WaL + (mh * 64 + l31) * 128 + lhi * 8;
#pragma unroll
    for (int j = 0; j < 4; ++j) {
      a1h0[j] = *(const halfx8*)(wa + j * 16);
      a1l0[j] = *(const halfx8*)(wa + 64 + j * 16);
      a1h1[j] = *(const halfx8*)(wa + 32 * 128 + j * 16);
      a1l1[j] = *(const halfx8*)(wa + 32 * 128 + 64 + j * 16);
    }
  }
  __syncthreads();

  // ---- GEMM1: h[128,64] = Wa @ z ----
  halfx8 gh0a, gh0b, gl0a, gl0b, gh1a, gh1b, gl1a, gl1b;
  {
    int colt = nh * 32 + l31;
    int sw = ((colt >> 3) & 3) << 5;
    const char* zr = sm + ZT_OFF + colt * 272;
    f32x16 hi0{}, hi1{}, lo0{}, lo1{};
#pragma unroll
    for (int ks = 0; ks < 12; ++ks) {
      int brow = (ks < 4) ? ks * 16 : ((ks < 8) ? (ks & 3) * 16 + 64 : (ks & 3) * 16);
      halfx8 bf = *(const halfx8*)(zr + ((brow * 2 + lhi * 16) ^ sw));
      if (ks < 4) {
        hi0 = MFMA(a1h0[ks], bf, hi0);
        hi1 = MFMA(a1h1[ks], bf, hi1);
      } else if (ks < 8) {
        lo0 = MFMA(a1h0[ks & 3], bf, lo0);
        lo1 = MFMA(a1h1[ks & 3], bf, lo1);
      } else {
        lo0 = MFMA(a1l0[ks & 3], bf, lo0);
        lo1 = MFMA(a1l1[ks & 3], bf, lo1);
      }
    }
#pragma unroll
    for (int r = 0; r < 16; ++r) {
      float ha = hi0[r] + lo0[r] * (1.f / 2048.f);
      float hb = hi1[r] + lo1[r] * (1.f / 2048.f);
      ha = fmaxf(ha, -30.f);
      hb = fmaxf(hb, -30.f);
      float ea = __expf(-ha), eb = __expf(-hb);
      float ga = (1.f - ea) * __builtin_amdgcn_rcpf(1.f + ea * ea);
      float gb = (1.f - eb) * __builtin_amdgcn_rcpf(1.f + eb * eb);
      half_t ga0 = (half_t)ga;
      half_t gb0 = (half_t)gb;
      half_t ga1 = (half_t)((ga - (float)ga0) * 2048.f);
      half_t gb1 = (half_t)((gb - (float)gb0) * 2048.f);
      if (r < 8) {
        gh0a[r] = ga0; gl0a[r] = ga1; gh1a[r] = gb0; gl1a[r] = gb1;
      } else {
        gh0b[r - 8] = ga0; gl0b[r - 8] = ga1; gh1b[r - 8] = gb0; gl1b[r - 8] = gb1;
      }
    }
    // gT write: K-col = mh*64 + tile*32 + lhi*16 + r (perm matches Wr repack)
    char* gr = sm + GT_OFF + colt * 528 + mh * 128 + lhi * 32;
    *(halfx8*)(gr)            = gh0a;
    *(halfx8*)(gr + 16)       = gh0b;
    *(halfx8*)(gr + 64)       = gh1a;
    *(halfx8*)(gr + 64 + 16)  = gh1b;
    *(halfx8*)(gr + 256)      = gl0a;
    *(halfx8*)(gr + 256 + 16) = gl0b;
    *(halfx8*)(gr + 320)      = gl1a;
    *(halfx8*)(gr + 320 + 16) = gl1b;
  }

  // ---- GEMM2 A-fragments (needed only after barrier; loads overlap barrier wait) ----
  halfx8 a2[12];
  {
    const half_t* wr = WrL + l31 * 256 + lhi * 8;
    if (nh == 0) {
#pragma unroll
      for (int j = 0; j < 8; ++j) a2[j] = *(const halfx8*)(wr + j * 16);
#pragma unroll
      for (int j = 8; j < 12; ++j) a2[j] = a2[j - 8];
    } else {
#pragma unroll
      for (int j = 0; j < 4; ++j) a2[j] = *(const halfx8*)(wr + 64 + j * 16);
#pragma unroll
      for (int j = 0; j < 8; ++j) a2[4 + j] = *(const halfx8*)(wr + 128 + j * 16);
    }
  }
  __syncthreads();

  // ---- GEMM2: skip[32,64] = Wr @ g ----
  {
    int kh = nh;
    int colt2 = mh * 32 + l31;
    const char* g2 = sm + GT_OFF + colt2 * 528 + lhi * 16;
    f32x16 shi{}, slo{};
    if (kh == 0) {
#pragma unroll
      for (int ks = 0; ks < 12; ++ks) {
        int brow = (ks < 8) ? ks * 16 : (ks - 8) * 16 + 128;
        halfx8 bf = *(const halfx8*)(g2 + brow * 2);
        if (ks < 8) shi = MFMA(a2[ks], bf, shi);
        else        slo = MFMA(a2[ks], bf, slo);
      }
    } else {
#pragma unroll
      for (int ks = 0; ks < 12; ++ks) {
        int brow = (ks < 4) ? (ks + 4) * 16 + 128 : (ks - 4) * 16;
        halfx8 bf = *(const halfx8*)(g2 + brow * 2);
        slo = MFMA(a2[ks], bf, slo);
      }
    }
    // skb partials (overlay zT; all waves past GEMM1 reads due to barrier above)
    float* skb = (float*)(sm + SKB_OFF) + kh * 32 * 68;
#pragma unroll
    for (int r = 0; r < 16; ++r) {
      int row = (r & 3) + 8 * (r >> 2) + 4 * lhi;
      skb[row * 68 + colt2] = shi[r] + slo[r] * (1.f / 2048.f);
    }
  }
  __syncthreads();

  // ---- writeout: resOut = resIn (global, L2-hot) + skip ----
  {
    int c = tid >> 3, tw = (tid & 7) * 8;
    const float* s0 = (const float*)(sm + SKB_OFF) + c * 68 + tw;
    const float* s1 = s0 + 32 * 68;
    size_t base = ((size_t)b * 32 + c) * T_LEN + t0 + tw;
#pragma unroll
    for (int v = 0; v < 8; v += 4) {
      float4 sa = *(const float4*)(s0 + v);
      float4 sb = *(const float4*)(s1 + v);
      float4 rv = *(const float4*)(resIn + base + v);
      float4 o;
      o.x = rv.x + sa.x + sb.x;
      o.y = rv.y + sa.y + sb.y;
      o.z = rv.z + sa.z + sb.z;
      o.w = rv.w + sa.w + sb.w;
      *(float4*)(resOut + base + v) = o;
    }
  }
}

// ---------------- end: relu(resF-res0) -> relu(We1@.) -> We2@. , MFMA split-2 ----------------
__global__ __launch_bounds__(512) void end_k(const float* __restrict__ resF,
                                             const float* __restrict__ res0,
                                             const half_t* __restrict__ We1S,
                                             const half_t* __restrict__ We2S,
                                             float* __restrict__ out) {
  __shared__ __align__(16) char sm[75776];
  const int H2T_OFF = 0, H1F_OFF = 0, H1T_OFF = 66560;
  int tid = threadIdx.x;
  int b = blockIdx.x / NTILE;
  int t0 = (blockIdx.x % NTILE) * TT;

  {
    int c = tid >> 4, tt4 = (tid & 15) * 4;
    size_t base = ((size_t)b * 32 + c) * T_LEN + t0 + tt4;
    float4 f = *(const float4*)(resF + base);
    float4 z = *(const float4*)(res0 + base);
    float* h1 = (float*)(sm + H1F_OFF) + c * 68 + tt4;
    h1[0] = fmaxf(f.x - z.x, 0.f);
    h1[1] = fmaxf(f.y - z.y, 0.f);
    h1[2] = fmaxf(f.z - z.z, 0.f);
    h1[3] = fmaxf(f.w - z.w, 0.f);
  }
  __syncthreads();
  {
    int t = tid & 63, cg = tid >> 6;
    const float* h1 = (const float*)(sm + H1F_OFF);
    halfx4 hi, lo;
#pragma unroll
    for (int j = 0; j < 4; ++j) {
      float v = h1[(cg * 4 + j) * 68 + t];
      half_t h = (half_t)v;
      hi[j] = h;
      lo[j] = (half_t)((v - (float)h) * 2048.f);
    }
    half_t* h1t = (half_t*)(sm + H1T_OFF) + t * 72;
    *(halfx4*)(h1t + cg * 4)      = hi;
    *(halfx4*)(h1t + 32 + cg * 4) = lo;
  }
  __syncthreads();

  int wave = tid >> 6, lane = tid & 63;
  int l31 = lane & 31, lhi = lane >> 5;

  f32x16 aHi0{}, aHi1{}, aLo0{}, aLo1{};
  {
    const char* h1t = sm + H1T_OFF;
    const half_t* wp = We1S + (wave * 32 + l31) * 64;
#pragma unroll
    for (int ks = 0; ks < 2; ++ks) {
      halfx8 hiA = *(const halfx8*)(wp + ks * 16 + lhi * 8);
      halfx8 loA = *(const halfx8*)(wp + 32 + ks * 16 + lhi * 8);
      const char* br0 = h1t + l31 * 144;
      const char* br1 = h1t + (32 + l31) * 144;
      halfx8 hiB0 = *(const halfx8*)(br0 + (ks * 16 + lhi * 8) * 2);
      halfx8 loB0 = *(const halfx8*)(br0 + (32 + ks * 16 + lhi * 8) * 2);
      halfx8 hiB1 = *(const halfx8*)(br1 + (ks * 16 + lhi * 8) * 2);
      halfx8 loB1 = *(const halfx8*)(br1 + (32 + ks * 16 + lhi * 8) * 2);
      aHi0 = MFMA(hiA, hiB0, aHi0);
      aLo0 = MFMA(hiA, loB0, aLo0);
      aLo0 = MFMA(loA, hiB0, aLo0);
      aHi1 = MFMA(hiA, hiB1, aHi1);
      aLo1 = MFMA(hiA, loB1, aLo1);
      aLo1 = MFMA(loA, hiB1, aLo1);
    }
  }
  {
#pragma unroll
    for (int n = 0; n < 2; ++n) {
      const f32x16& aH = n ? aHi1 : aHi0;
      const f32x16& aL = n ? aLo1 : aLo0;
      int t = n * 32 + l31;
      half_t* row = (half_t*)(sm + H2T_OFF) + t * 520;
#pragma unroll
      for (int g = 0; g < 4; ++g) {
        halfx4 hi, lo;
#pragma unroll
        for (int j = 0; j < 4; ++j) {
          int r = g * 4 + j;
          float v = aH[r] + aL[r] * (1.f / 2048.f);
          v = fmaxf(v, 0.f);
          half_t h = (half_t)v;
          hi[j] = h;
          lo[j] = (half_t)((v - (float)h) * 2048.f);
        }
        int col = wave * 32 + g * 8 + lhi * 4;
        *(halfx4*)(row + col)       = hi;
        *(halfx4*)(row + 256 + col) = lo;
      }
    }
  }
  __syncthreads();

  f32x16 bHi0{}, bHi1{}, bLo0{}, bLo1{};
  {
    const half_t* wp = We2S + (size_t)(wave * 32 + l31) * 512;
    const char* h2t = sm + H2T_OFF;
#pragma unroll 2
    for (int ks = 0; ks < 16; ++ks) {
      halfx8 hiA = *(const halfx8*)(wp + ks * 16 + lhi * 8);
      halfx8 loA = *(const halfx8*)(wp + 256 + ks * 16 + lhi * 8);
      const char* br0 = h2t + l31 * 1040;
      const char* br1 = h2t + (32 + l31) * 1040;
      halfx8 hiB0 = *(const halfx8*)(br0 + (ks * 16 + lhi * 8) * 2);
      halfx8 loB0 = *(const halfx8*)(br0 + (256 + ks * 16 + lhi * 8) * 2);
      halfx8 hiB1 = *(const halfx8*)(br1 + (ks * 16 + lhi * 8) * 2);
      halfx8 loB1 = *(const halfx8*)(br1 + (256 + ks * 16 + lhi * 8) * 2);
      bHi0 = MFMA(hiA, hiB0, bHi0);
      bLo0 = MFMA(hiA, loB0, bLo0);
      bLo0 = MFMA(loA, hiB0, bLo0);
      bHi1 = MFMA(hiA, hiB1, bHi1);
      bLo1 = MFMA(hiA, loB1, bLo1);
      bLo1 = MFMA(loA, hiB1, bLo1);
    }
  }
  {
#pragma unroll
    for (int n = 0; n < 2; ++n) {
      const f32x16& bH = n ? bHi1 : bHi0;
      const f32x16& bL = n ? bLo1 : bLo0;
      int t = t0 + n * 32 + l31;
#pragma unroll
      for (int r = 0; r < 16; ++r) {
        int o = wave * 32 + (r & 3) + 8 * (r >> 2) + 4 * lhi;
        out[((size_t)b * 256 + o) * T_LEN + t] = bH[r] + bL[r] * (1.f / 2048.f);
      }
    }
  }
}

extern "C" void kernel_launch(void* const* d_in, const int* in_sizes, int n_in,
                              void* d_out, int out_size, void* d_ws, size_t ws_size,
                              hipStream_t stream) {
  const float* x   = (const float*)d_in[0];
  const float* Wst = (const float*)d_in[1];
  const float* Wd  = (const float*)d_in[2];
  const float* Wr  = (const float*)d_in[3];
  const float* We1 = (const float*)d_in[4];
  const float* We2 = (const float*)d_in[5];
  float* out = (float*)d_out;
  float* ws = (float*)d_ws;

  float* resA = ws;                        // start output (skips = resF - resA)
  float* resB = resA + N_RES;
  float* resC = resB + N_RES;
  half_t* WaG  = (half_t*)(resC + N_RES);  // 40*16384
  half_t* WrG  = WaG + 40 * 16384;         // 40*8192
  float*  WsT  = (float*)(WrG + 40 * 8192);
  half_t* We1S = (half_t*)(WsT + 8192);    // 16384
  half_t* We2S = We1S + 16384;             // 131072

  repack_k<<<2560, 256, 0, stream>>>(Wd, Wr, Wst, We1, We2, WaG, WrG, WsT, We1S, We2S);
  start_k<<<NBLK, 256, 0, stream>>>(x, WsT, resA);

  const float* rin = resA;
  for (int l = 0; l < 40; ++l) {
    float* rout = (l & 1) ? resC : resB;
    layer_k<<<NBLK, 256, 0, stream>>>(rin, rout, WaG + l * 16384, WrG + l * 8192,
                                      1 << (l % 10));
    rin = rout;
  }
  end_k<<<NBLK, 512, 0, stream>>>(rin, resA, We1S, We2S, out);
}

// Round 6
// 1183.348 us; speedup vs baseline: 1.2905x; 1.2905x over previous
//
#include <hip/hip_runtime.h>
#include <math.h>

#define T_LEN 16000
#define NTILE 250          // time tiles per batch row (16000/64)
#define TT 64              // time tile
#define NBLK 2000          // 8 * 250
#define LGRID 500          // layer grid: 4 strided tiles per block

static const int N_RES = 8 * 32 * T_LEN;   // 4,096,000 floats per residual buffer

typedef _Float16 half_t;
typedef __attribute__((ext_vector_type(8))) _Float16 halfx8;
typedef __attribute__((ext_vector_type(4))) _Float16 halfx4;
typedef __attribute__((ext_vector_type(16))) float f32x16;
typedef unsigned int uint32;
typedef unsigned short ushort16;

#define MFMA(a, b, c) __builtin_amdgcn_mfma_f32_32x32x16_f16((a), (b), (c), 0, 0, 0)

static __device__ inline uint32 packpair(float a, float b) {
  half_t ha = (half_t)a, hb = (half_t)b;
  return (uint32)__builtin_bit_cast(ushort16, ha) |
         ((uint32)__builtin_bit_cast(ushort16, hb) << 16);
}

// ---------------- weight repack ----------------
// WaG[l][o=0..127][k=0..127]: k<64: k=2c+s -> hi(Wd[l][o][c][s]); k>=64: lo*2048 of same
// WrG[l][o2=0..31][k=0..255]: g-register perm; kk=k&127: ks=kk>>4, lh=(kk>>3)&1, j=kk&7;
//   mh=ks>>2, til=(ks>>1)&1, ab=ks&1; m = mh*64+til*32+ab*16+(j&3)+8*(j>>2)+4*lh
//   k<128 hi of Wr[l][m][o2]^T, k>=128 lo*2048  (so GEMM2's B-operand = gate regs directly)
// We1S[o][k=0..63]: k<32 hi We1[o][k], k>=32 lo*2048
// We2S[o][k=0..511]: k<256 hi We2[o][k], k>=256 lo*2048
__global__ __launch_bounds__(256) void repack_k(
    const float* __restrict__ Wd, const float* __restrict__ Wr,
    const float* __restrict__ Ws, const float* __restrict__ We1,
    const float* __restrict__ We2,
    half_t* __restrict__ WaG, half_t* __restrict__ WrG, float* __restrict__ WsT,
    half_t* __restrict__ We1S, half_t* __restrict__ We2S) {
  int i = blockIdx.x * 256 + threadIdx.x;
  if (i < 40 * 128 * 128) {
    int l = i >> 14, r = i & 16383, o = r >> 7, k = r & 127;
    int kk = k & 63, c = kk >> 1, s = kk & 1;
    float w = Wd[(((l * 128 + o) * 32 + c) << 1) + s];
    half_t w0 = (half_t)w;
    WaG[i] = (k < 64) ? w0 : (half_t)((w - (float)w0) * 2048.f);
  }
  if (i < 40 * 32 * 256) {
    int l = i >> 13, r = i & 8191, o2 = r >> 8, k = r & 255;
    int kk = k & 127;
    int ks = kk >> 4, lh = (kk >> 3) & 1, j = kk & 7;
    int mh = ks >> 2, til = (ks >> 1) & 1, ab = ks & 1;
    int m = mh * 64 + til * 32 + ab * 16 + (j & 3) + ((j >> 2) << 3) + lh * 4;
    float w = Wr[(l * 32 + o2) * 128 + m];
    half_t w0 = (half_t)w;
    WrG[i] = (k < 128) ? w0 : (half_t)((w - (float)w0) * 2048.f);
  }
  if (i < 8192) {
    int c = i >> 5, o = i & 31;
    WsT[i] = Ws[o * 256 + c];
  }
  if (i < 16384) {
    int o = i >> 6, k = i & 63;
    float w = We1[o * 32 + (k & 31)];
    half_t w0 = (half_t)w;
    We1S[i] = (k < 32) ? w0 : (half_t)((w - (float)w0) * 2048.f);
  }
  if (i < 131072) {
    int o = i >> 9, k = i & 511;
    float w = We2[o * 256 + (k & 255)];
    half_t w0 = (half_t)w;
    We2S[i] = (k < 256) ? w0 : (half_t)((w - (float)w0) * 2048.f);
  }
}

// ---------------- start 1x1 conv (f32): residual = W_start @ x ----------------
__global__ __launch_bounds__(256) void start_k(const float* __restrict__ x,
                                               const float* __restrict__ WsT,
                                               float* __restrict__ res) {
  __shared__ float xs[32][68];
  int b = blockIdx.x / NTILE;
  int t0 = (blockIdx.x % NTILE) * TT;
  int tid = threadIdx.x;
  int o = tid & 31, tg = (tid >> 5) * 8;
  int lr = tid >> 3, lt = (tid & 7) * 8;
  float acc[8];
#pragma unroll
  for (int j = 0; j < 8; ++j) acc[j] = 0.f;
  for (int cc = 0; cc < 8; ++cc) {
    __syncthreads();
    const float* xp = x + ((size_t)b * 256 + cc * 32 + lr) * T_LEN + t0 + lt;
    *(float4*)&xs[lr][lt]     = *(const float4*)xp;
    *(float4*)&xs[lr][lt + 4] = *(const float4*)(xp + 4);
    __syncthreads();
#pragma unroll 4
    for (int c = 0; c < 32; ++c) {
      float w = WsT[(cc * 32 + c) * 32 + o];
      const float* xr = &xs[c][tg];
#pragma unroll
      for (int j = 0; j < 8; ++j) acc[j] += w * xr[j];
    }
  }
  float* rp = res + ((size_t)b * 32 + o) * T_LEN + t0 + tg;
  *(float4*)rp       = make_float4(acc[0], acc[1], acc[2], acc[3]);
  *(float4*)(rp + 4) = make_float4(acc[4], acc[5], acc[6], acc[7]);
}

// ---------------- fused WaveNet layer: GEMM2 B-operand in registers, no gT ----------------
// LDS map (bytes):
//   [0,     17408)  zT  64 rows x 272B (pair-interleaved, XOR-swizzled) | skb overlay (2x32x68 f32)
//   [17408, 26112)  cur32 32 x 68 f32
__global__ __launch_bounds__(256, 3) void layer_k(const float* __restrict__ resIn,
                                                  float* __restrict__ resOut,
                                                  const half_t* __restrict__ WaL,
                                                  const half_t* __restrict__ WrL, int d) {
  __shared__ __align__(16) char sm[26112];
  const int ZT_OFF = 0, SKB_OFF = 0, CUR_OFF = 17408;
  int tid = threadIdx.x;
  int wave = tid >> 6, lane = tid & 63;
  int l31 = lane & 31, lhi = lane >> 5;
  int mh = wave & 1, nh = wave >> 1;   // wave owns m-half mh, t-half nh (both GEMMs)

  for (int ti = 0; ti < 4; ++ti) {
    int tile = blockIdx.x + ti * LGRID;
    int b = tile / NTILE;
    int t0 = (tile - b * NTILE) * TT;

    // ---- stage zT + cur32 ----
    {
      int c = tid >> 3, tw = (tid & 7) * 8;
      const float* rip = resIn + ((size_t)b * 32 + c) * T_LEN;
      float cv[8], pv[8];
      *(float4*)cv       = *(const float4*)(rip + t0 + tw);
      *(float4*)(cv + 4) = *(const float4*)(rip + t0 + tw + 4);
      int tp = t0 + tw - d;
      if (tp >= 0 && (d & 3) == 0) {
        *(float4*)pv       = *(const float4*)(rip + tp);
        *(float4*)(pv + 4) = *(const float4*)(rip + tp + 4);
      } else {
#pragma unroll
        for (int j = 0; j < 8; ++j) {
          int q = tp + j;
          pv[j] = (q >= 0) ? rip[q] : 0.f;
        }
      }
      float* cw = (float*)(sm + CUR_OFF) + c * 68 + tw;
      *(float4*)cw       = *(const float4*)cv;
      *(float4*)(cw + 4) = *(const float4*)(cv + 4);
#pragma unroll
      for (int j = 0; j < 8; ++j) {
        int t = tw + j;
        int sw = ((t >> 3) & 3) << 5;
        char* zrow = sm + ZT_OFF + t * 272;
        half_t p0 = (half_t)pv[j];
        half_t c0 = (half_t)cv[j];
        float pl = (pv[j] - (float)p0) * 2048.f;
        float cl = (cv[j] - (float)c0) * 2048.f;
        *(uint32*)(zrow + ((c * 4) ^ sw))       = packpair(pv[j], cv[j]);
        *(uint32*)(zrow + ((c * 4 + 128) ^ sw)) = packpair(pl, cl);
      }
    }
    __syncthreads();

    // ---- GEMM1 A-fragments (L1/L2-hot; reloaded per tile to cap live range) ----
    halfx8 a1h0[4], a1l0[4], a1h1[4], a1l1[4];
    {
      const half_t* wa = WaL + (mh * 64 + l31) * 128 + lhi * 8;
#pragma unroll
      for (int j = 0; j < 4; ++j) {
        a1h0[j] = *(const halfx8*)(wa + j * 16);
        a1l0[j] = *(const halfx8*)(wa + 64 + j * 16);
        a1h1[j] = *(const halfx8*)(wa + 32 * 128 + j * 16);
        a1l1[j] = *(const halfx8*)(wa + 32 * 128 + 64 + j * 16);
      }
    }

    // ---- GEMM1: h[128,64] = Wa @ z ----
    f32x16 hi0{}, hi1{}, lo0{}, lo1{};
    {
      int colt = nh * 32 + l31;
      int sw = ((colt >> 3) & 3) << 5;
      const char* zr = sm + ZT_OFF + colt * 272;
#pragma unroll
      for (int ks = 0; ks < 12; ++ks) {
        int brow = (ks < 4) ? ks * 16 : ((ks < 8) ? (ks & 3) * 16 + 64 : (ks & 3) * 16);
        halfx8 bf = *(const halfx8*)(zr + ((brow * 2 + lhi * 16) ^ sw));
        if (ks < 4) {
          hi0 = MFMA(a1h0[ks], bf, hi0);
          hi1 = MFMA(a1h1[ks], bf, hi1);
        } else if (ks < 8) {
          lo0 = MFMA(a1h0[ks & 3], bf, lo0);
          lo1 = MFMA(a1h1[ks & 3], bf, lo1);
        } else {
          lo0 = MFMA(a1l0[ks & 3], bf, lo0);
          lo1 = MFMA(a1l1[ks & 3], bf, lo1);
        }
      }
    }

    // ---- GEMM2 A-fragments: Wr K-chunk for this wave (overlaps gate VALU below) ----
    halfx8 wrHi[4], wrLo[4];
    {
      const half_t* wr = WrL + l31 * 256 + mh * 64 + lhi * 8;
#pragma unroll
      for (int q = 0; q < 4; ++q) {
        wrHi[q] = *(const halfx8*)(wr + q * 16);
        wrLo[q] = *(const halfx8*)(wr + 128 + q * 16);
      }
    }

    // ---- gate -> g splits packed as GEMM2 B-fragments (registers, no LDS) ----
    halfx8 gh0a, gh0b, gl0a, gl0b, gh1a, gh1b, gl1a, gl1b;
    {
#pragma unroll
      for (int r = 0; r < 16; ++r) {
        float ha = hi0[r] + lo0[r] * (1.f / 2048.f);
        float hb = hi1[r] + lo1[r] * (1.f / 2048.f);
        ha = fmaxf(ha, -30.f);
        hb = fmaxf(hb, -30.f);
        float ea = __expf(-ha), eb = __expf(-hb);
        float ga = (1.f - ea) * __builtin_amdgcn_rcpf(1.f + ea * ea);
        float gb = (1.f - eb) * __builtin_amdgcn_rcpf(1.f + eb * eb);
        half_t ga0 = (half_t)ga;
        half_t gb0 = (half_t)gb;
        half_t ga1 = (half_t)((ga - (float)ga0) * 2048.f);
        half_t gb1 = (half_t)((gb - (float)gb0) * 2048.f);
        if (r < 8) {
          gh0a[r] = ga0; gl0a[r] = ga1; gh1a[r] = gb0; gl1a[r] = gb1;
        } else {
          gh0b[r - 8] = ga0; gl0b[r - 8] = ga1; gh1b[r - 8] = gb0; gl1b[r - 8] = gb1;
        }
      }
    }

    // ---- GEMM2: skip partial (this wave's K-quarter), pure-register operands ----
    f32x16 shi{}, slo{};
    {
      shi = MFMA(wrHi[0], gh0a, shi);
      shi = MFMA(wrHi[1], gh0b, shi);
      shi = MFMA(wrHi[2], gh1a, shi);
      shi = MFMA(wrHi[3], gh1b, shi);
      slo = MFMA(wrHi[0], gl0a, slo);
      slo = MFMA(wrHi[1], gl0b, slo);
      slo = MFMA(wrHi[2], gl1a, slo);
      slo = MFMA(wrHi[3], gl1b, slo);
      slo = MFMA(wrLo[0], gh0a, slo);
      slo = MFMA(wrLo[1], gh0b, slo);
      slo = MFMA(wrLo[2], gh1a, slo);
      slo = MFMA(wrLo[3], gh1b, slo);
    }
    __syncthreads();   // all zT reads done; safe to overlay with skb

    // ---- skb partials (overlay zT): skb[mh][row][nh*32+col] ----
    {
      float* skb = (float*)(sm + SKB_OFF) + mh * 32 * 68;
#pragma unroll
      for (int r = 0; r < 16; ++r) {
        int row = (r & 3) + 8 * (r >> 2) + 4 * lhi;
        skb[row * 68 + nh * 32 + l31] = shi[r] + slo[r] * (1.f / 2048.f);
      }
    }
    __syncthreads();

    // ---- writeout: resOut = cur + skb0 + skb1 ----
    {
      int c = tid >> 3, tw = (tid & 7) * 8;
      const float* s0 = (const float*)(sm + SKB_OFF) + c * 68 + tw;
      const float* s1 = s0 + 32 * 68;
      const float* cu = (const float*)(sm + CUR_OFF) + c * 68 + tw;
      size_t base = ((size_t)b * 32 + c) * T_LEN + t0 + tw;
#pragma unroll
      for (int v = 0; v < 8; v += 4) {
        float4 sa = *(const float4*)(s0 + v);
        float4 sb = *(const float4*)(s1 + v);
        float4 cv = *(const float4*)(cu + v);
        float4 o;
        o.x = cv.x + sa.x + sb.x;
        o.y = cv.y + sa.y + sb.y;
        o.z = cv.z + sa.z + sb.z;
        o.w = cv.w + sa.w + sb.w;
        *(float4*)(resOut + base + v) = o;
      }
    }
    __syncthreads();
  }
}

// ---------------- end: relu(resF-res0) -> relu(We1@.) -> We2@. , MFMA split-2 ----------------
__global__ __launch_bounds__(512) void end_k(const float* __restrict__ resF,
                                             const float* __restrict__ res0,
                                             const half_t* __restrict__ We1S,
                                             const half_t* __restrict__ We2S,
                                             float* __restrict__ out) {
  __shared__ __align__(16) char sm[75776];
  const int H2T_OFF = 0, H1F_OFF = 0, H1T_OFF = 66560;
  int tid = threadIdx.x;
  int b = blockIdx.x / NTILE;
  int t0 = (blockIdx.x % NTILE) * TT;

  {
    int c = tid >> 4, tt4 = (tid & 15) * 4;
    size_t base = ((size_t)b * 32 + c) * T_LEN + t0 + tt4;
    float4 f = *(const float4*)(resF + base);
    float4 z = *(const float4*)(res0 + base);
    float* h1 = (float*)(sm + H1F_OFF) + c * 68 + tt4;
    h1[0] = fmaxf(f.x - z.x, 0.f);
    h1[1] = fmaxf(f.y - z.y, 0.f);
    h1[2] = fmaxf(f.z - z.z, 0.f);
    h1[3] = fmaxf(f.w - z.w, 0.f);
  }
  __syncthreads();
  {
    int t = tid & 63, cg = tid >> 6;
    const float* h1 = (const float*)(sm + H1F_OFF);
    halfx4 hi, lo;
#pragma unroll
    for (int j = 0; j < 4; ++j) {
      float v = h1[(cg * 4 + j) * 68 + t];
      half_t h = (half_t)v;
      hi[j] = h;
      lo[j] = (half_t)((v - (float)h) * 2048.f);
    }
    half_t* h1t = (half_t*)(sm + H1T_OFF) + t * 72;
    *(halfx4*)(h1t + cg * 4)      = hi;
    *(halfx4*)(h1t + 32 + cg * 4) = lo;
  }
  __syncthreads();

  int wave = tid >> 6, lane = tid & 63;
  int l31 = lane & 31, lhi = lane >> 5;

  f32x16 aHi0{}, aHi1{}, aLo0{}, aLo1{};
  {
    const char* h1t = sm + H1T_OFF;
    const half_t* wp = We1S + (wave * 32 + l31) * 64;
#pragma unroll
    for (int ks = 0; ks < 2; ++ks) {
      halfx8 hiA = *(const halfx8*)(wp + ks * 16 + lhi * 8);
      halfx8 loA = *(const halfx8*)(wp + 32 + ks * 16 + lhi * 8);
      const char* br0 = h1t + l31 * 144;
      const char* br1 = h1t + (32 + l31) * 144;
      halfx8 hiB0 = *(const halfx8*)(br0 + (ks * 16 + lhi * 8) * 2);
      halfx8 loB0 = *(const halfx8*)(br0 + (32 + ks * 16 + lhi * 8) * 2);
      halfx8 hiB1 = *(const halfx8*)(br1 + (ks * 16 + lhi * 8) * 2);
      halfx8 loB1 = *(const halfx8*)(br1 + (32 + ks * 16 + lhi * 8) * 2);
      aHi0 = MFMA(hiA, hiB0, aHi0);
      aLo0 = MFMA(hiA, loB0, aLo0);
      aLo0 = MFMA(loA, hiB0, aLo0);
      aHi1 = MFMA(hiA, hiB1, aHi1);
      aLo1 = MFMA(hiA, loB1, aLo1);
      aLo1 = MFMA(loA, hiB1, aLo1);
    }
  }
  {
#pragma unroll
    for (int n = 0; n < 2; ++n) {
      const f32x16& aH = n ? aHi1 : aHi0;
      const f32x16& aL = n ? aLo1 : aLo0;
      int t = n * 32 + l31;
      half_t* row = (half_t*)(sm + H2T_OFF) + t * 520;
#pragma unroll
      for (int g = 0; g < 4; ++g) {
        halfx4 hi, lo;
#pragma unroll
        for (int j = 0; j < 4; ++j) {
          int r = g * 4 + j;
          float v = aH[r] + aL[r] * (1.f / 2048.f);
          v = fmaxf(v, 0.f);
          half_t h = (half_t)v;
          hi[j] = h;
          lo[j] = (half_t)((v - (float)h) * 2048.f);
        }
        int col = wave * 32 + g * 8 + lhi * 4;
        *(halfx4*)(row + col)       = hi;
        *(halfx4*)(row + 256 + col) = lo;
      }
    }
  }
  __syncthreads();

  f32x16 bHi0{}, bHi1{}, bLo0{}, bLo1{};
  {
    const half_t* wp = We2S + (size_t)(wave * 32 + l31) * 512;
    const char* h2t = sm + H2T_OFF;
#pragma unroll 2
    for (int ks = 0; ks < 16; ++ks) {
      halfx8 hiA = *(const halfx8*)(wp + ks * 16 + lhi * 8);
      halfx8 loA = *(const halfx8*)(wp + 256 + ks * 16 + lhi * 8);
      const char* br0 = h2t + l31 * 1040;
      const char* br1 = h2t + (32 + l31) * 1040;
      halfx8 hiB0 = *(const halfx8*)(br0 + (ks * 16 + lhi * 8) * 2);
      halfx8 loB0 = *(const halfx8*)(br0 + (256 + ks * 16 + lhi * 8) * 2);
      halfx8 hiB1 = *(const halfx8*)(br1 + (ks * 16 + lhi * 8) * 2);
      halfx8 loB1 = *(const halfx8*)(br1 + (256 + ks * 16 + lhi * 8) * 2);
      bHi0 = MFMA(hiA, hiB0, bHi0);
      bLo0 = MFMA(hiA, loB0, bLo0);
      bLo0 = MFMA(loA, hiB0, bLo0);
      bHi1 = MFMA(hiA, hiB1, bHi1);
      bLo1 = MFMA(hiA, loB1, bLo1);
      bLo1 = MFMA(loA, hiB1, bLo1);
    }
  }
  {
#pragma unroll
    for (int n = 0; n < 2; ++n) {
      const f32x16& bH = n ? bHi1 : bHi0;
      const f32x16& bL = n ? bLo1 : bLo0;
      int t = t0 + n * 32 + l31;
#pragma unroll
      for (int r = 0; r < 16; ++r) {
        int o = wave * 32 + (r & 3) + 8 * (r >> 2) + 4 * lhi;
        out[((size_t)b * 256 + o) * T_LEN + t] = bH[r] + bL[r] * (1.f / 2048.f);
      }
    }
  }
}

extern "C" void kernel_launch(void* const* d_in, const int* in_sizes, int n_in,
                              void* d_out, int out_size, void* d_ws, size_t ws_size,
                              hipStream_t stream) {
  const float* x   = (const float*)d_in[0];
  const float* Wst = (const float*)d_in[1];
  const float* Wd  = (const float*)d_in[2];
  const float* Wr  = (const float*)d_in[3];
  const float* We1 = (const float*)d_in[4];
  const float* We2 = (const float*)d_in[5];
  float* out = (float*)d_out;
  float* ws = (float*)d_ws;

  float* resA = ws;                        // start output (skips = resF - resA)
  float* resB = resA + N_RES;
  float* resC = resB + N_RES;
  half_t* WaG  = (half_t*)(resC + N_RES);  // 40*16384
  half_t* WrG  = WaG + 40 * 16384;         // 40*8192
  float*  WsT  = (float*)(WrG + 40 * 8192);
  half_t* We1S = (half_t*)(WsT + 8192);    // 16384
  half_t* We2S = We1S + 16384;             // 131072

  repack_k<<<2560, 256, 0, stream>>>(Wd, Wr, Wst, We1, We2, WaG, WrG, WsT, We1S, We2S);
  start_k<<<NBLK, 256, 0, stream>>>(x, WsT, resA);

  const float* rin = resA;
  for (int l = 0; l < 40; ++l) {
    float* rout = (l & 1) ? resC : resB;
    layer_k<<<LGRID, 256, 0, stream>>>(rin, rout, WaG + l * 16384, WrG + l * 8192,
                                       1 << (l % 10));
    rin = rout;
  }
  end_k<<<NBLK, 512, 0, stream>>>(rin, resA, We1S, We2S, out);
}

// Round 8
// 1050.477 us; speedup vs baseline: 1.4538x; 1.1265x over previous
//
#include <hip/hip_runtime.h>
#include <math.h>

#define T_LEN 16000
#define NTILE 250          // time tiles per batch row (16000/64)
#define TT 64              // time tile
#define NBLK 2000          // 8 * 250
#define LGRID 500          // layer grid: 4 strided tiles per block

static const int N_RES = 8 * 32 * T_LEN;   // 4,096,000 floats per residual buffer

typedef _Float16 half_t;
typedef __attribute__((ext_vector_type(8))) _Float16 halfx8;
typedef __attribute__((ext_vector_type(4))) _Float16 halfx4;
typedef __attribute__((ext_vector_type(16))) float f32x16;
typedef unsigned int uint32;
typedef unsigned short ushort16;

#define MFMA(a, b, c) __builtin_amdgcn_mfma_f32_32x32x16_f16((a), (b), (c), 0, 0, 0)

static __device__ inline uint32 packpair(float a, float b) {
  half_t ha = (half_t)a, hb = (half_t)b;
  return (uint32)__builtin_bit_cast(ushort16, ha) |
         ((uint32)__builtin_bit_cast(ushort16, hb) << 16);
}

// ---------------- weight repack ----------------
// WaG[l][o=0..127][k=0..127]: k<64: k=2c+s -> hi(Wd[l][o][c][s]); k>=64: lo*2048 of same
// WrG[l][o2=0..31][k=0..255]: g-register perm; kk=k&127: ks=kk>>4, lh=(kk>>3)&1, j=kk&7;
//   mh=ks>>2, til=(ks>>1)&1, ab=ks&1; m = mh*64+til*32+ab*16+(j&3)+8*(j>>2)+4*lh
//   k<128 hi of Wr[l][m][o2]^T, k>=128 lo*2048  (GEMM2's B-operand = gate regs directly)
// We1S[o][k=0..63]: k<32 hi We1[o][k], k>=32 lo*2048
// We2S[o][k=0..511]: k<256 hi We2[o][k], k>=256 lo*2048
__global__ __launch_bounds__(256) void repack_k(
    const float* __restrict__ Wd, const float* __restrict__ Wr,
    const float* __restrict__ Ws, const float* __restrict__ We1,
    const float* __restrict__ We2,
    half_t* __restrict__ WaG, half_t* __restrict__ WrG, float* __restrict__ WsT,
    half_t* __restrict__ We1S, half_t* __restrict__ We2S) {
  int i = blockIdx.x * 256 + threadIdx.x;
  if (i < 40 * 128 * 128) {
    int l = i >> 14, r = i & 16383, o = r >> 7, k = r & 127;
    int kk = k & 63, c = kk >> 1, s = kk & 1;
    float w = Wd[(((l * 128 + o) * 32 + c) << 1) + s];
    half_t w0 = (half_t)w;
    WaG[i] = (k < 64) ? w0 : (half_t)((w - (float)w0) * 2048.f);
  }
  if (i < 40 * 32 * 256) {
    int l = i >> 13, r = i & 8191, o2 = r >> 8, k = r & 255;
    int kk = k & 127;
    int ks = kk >> 4, lh = (kk >> 3) & 1, j = kk & 7;
    int mh = ks >> 2, til = (ks >> 1) & 1, ab = ks & 1;
    int m = mh * 64 + til * 32 + ab * 16 + (j & 3) + ((j >> 2) << 3) + lh * 4;
    float w = Wr[(l * 32 + o2) * 128 + m];
    half_t w0 = (half_t)w;
    WrG[i] = (k < 128) ? w0 : (half_t)((w - (float)w0) * 2048.f);
  }
  if (i < 8192) {
    int c = i >> 5, o = i & 31;
    WsT[i] = Ws[o * 256 + c];
  }
  if (i < 16384) {
    int o = i >> 6, k = i & 63;
    float w = We1[o * 32 + (k & 31)];
    half_t w0 = (half_t)w;
    We1S[i] = (k < 32) ? w0 : (half_t)((w - (float)w0) * 2048.f);
  }
  if (i < 131072) {
    int o = i >> 9, k = i & 511;
    float w = We2[o * 256 + (k & 255)];
    half_t w0 = (half_t)w;
    We2S[i] = (k < 256) ? w0 : (half_t)((w - (float)w0) * 2048.f);
  }
}

// ---------------- start 1x1 conv (f32): residual = W_start @ x ----------------
__global__ __launch_bounds__(256) void start_k(const float* __restrict__ x,
                                               const float* __restrict__ WsT,
                                               float* __restrict__ res) {
  __shared__ float xs[32][68];
  int b = blockIdx.x / NTILE;
  int t0 = (blockIdx.x % NTILE) * TT;
  int tid = threadIdx.x;
  int o = tid & 31, tg = (tid >> 5) * 8;
  int lr = tid >> 3, lt = (tid & 7) * 8;
  float acc[8];
#pragma unroll
  for (int j = 0; j < 8; ++j) acc[j] = 0.f;
  for (int cc = 0; cc < 8; ++cc) {
    __syncthreads();
    const float* xp = x + ((size_t)b * 256 + cc * 32 + lr) * T_LEN + t0 + lt;
    *(float4*)&xs[lr][lt]     = *(const float4*)xp;
    *(float4*)&xs[lr][lt + 4] = *(const float4*)(xp + 4);
    __syncthreads();
#pragma unroll 4
    for (int c = 0; c < 32; ++c) {
      float w = WsT[(cc * 32 + c) * 32 + o];
      const float* xr = &xs[c][tg];
#pragma unroll
      for (int j = 0; j < 8; ++j) acc[j] += w * xr[j];
    }
  }
  float* rp = res + ((size_t)b * 32 + o) * T_LEN + t0 + tg;
  *(float4*)rp       = make_float4(acc[0], acc[1], acc[2], acc[3]);
  *(float4*)(rp + 4) = make_float4(acc[4], acc[5], acc[6], acc[7]);
}

// ---------------- fused WaveNet layer: register prefetch pipeline ----------------
// LDS: zT 64 rows x 272B (pair-interleaved, XOR-swizzled) | skb overlay (2x32x68 f32)
#define LOAD_TILE(TI, CV, PV)                                              \
  {                                                                        \
    int tl_ = blockIdx.x + (TI) * LGRID;                                   \
    int bb_ = tl_ / NTILE;                                                 \
    int tb_ = (tl_ - bb_ * NTILE) * TT;                                    \
    const float* rip_ = resIn + ((size_t)bb_ * 32 + cth) * T_LEN;          \
    *(float4*)(CV)       = *(const float4*)(rip_ + tb_ + twh);             \
    *(float4*)((CV) + 4) = *(const float4*)(rip_ + tb_ + twh + 4);         \
    int tp_ = tb_ + twh - d;                                               \
    if (tp_ >= 0 && (d & 3) == 0) {                                        \
      *(float4*)(PV)       = *(const float4*)(rip_ + tp_);                 \
      *(float4*)((PV) + 4) = *(const float4*)(rip_ + tp_ + 4);             \
    } else {                                                               \
      _Pragma("unroll")                                                    \
      for (int j_ = 0; j_ < 8; ++j_) {                                     \
        int q_ = tp_ + j_;                                                 \
        (PV)[j_] = (q_ >= 0) ? rip_[q_] : 0.f;                             \
      }                                                                    \
    }                                                                      \
  }

#define TILE_BODY(TI, CV, PV, NCV, NPV, PREF)                                  \
  {                                                                            \
    int tile = blockIdx.x + (TI) * LGRID;                                      \
    int b = tile / NTILE;                                                      \
    int t0 = (tile - b * NTILE) * TT;                                          \
    /* ---- stage zT from regs ---- */                                         \
    _Pragma("unroll")                                                          \
    for (int j = 0; j < 8; ++j) {                                              \
      int t = twh + j;                                                         \
      int sw = ((t >> 3) & 3) << 5;                                            \
      char* zrow = sm + t * 272;                                               \
      half_t p0 = (half_t)(PV)[j];                                             \
      half_t c0 = (half_t)(CV)[j];                                             \
      float pl = ((PV)[j] - (float)p0) * 2048.f;                               \
      float cl = ((CV)[j] - (float)c0) * 2048.f;                               \
      *(uint32*)(zrow + ((cth * 4) ^ sw))       = packpair((PV)[j], (CV)[j]);  \
      *(uint32*)(zrow + ((cth * 4 + 128) ^ sw)) = packpair(pl, cl);            \
    }                                                                          \
    __syncthreads();                                                           \
    /* ---- prefetch next tile's activations (latency hides under GEMMs) */   \
    if (PREF) { LOAD_TILE((TI) + 1, NCV, NPV); }                               \
    /* ---- GEMM1: h[128,64] = Wa @ z ---- */                                  \
    f32x16 hi0{}, hi1{}, lo0{}, lo1{};                                         \
    {                                                                          \
      int colt = nh * 32 + l31;                                                \
      int sw = ((colt >> 3) & 3) << 5;                                         \
      const char* zr = sm + colt * 272;                                        \
      _Pragma("unroll")                                                        \
      for (int ks = 0; ks < 12; ++ks) {                                        \
        int brow = (ks < 4) ? ks * 16                                          \
                            : ((ks < 8) ? (ks & 3) * 16 + 64 : (ks & 3) * 16); \
        halfx8 bf = *(const halfx8*)(zr + ((brow * 2 + lhi * 16) ^ sw));       \
        if (ks < 4) {                                                          \
          hi0 = MFMA(a1h0[ks], bf, hi0);                                       \
          hi1 = MFMA(a1h1[ks], bf, hi1);                                       \
        } else if (ks < 8) {                                                   \
          lo0 = MFMA(a1h0[ks & 3], bf, lo0);                                   \
          lo1 = MFMA(a1h1[ks & 3], bf, lo1);                                   \
        } else {                                                               \
          lo0 = MFMA(a1l0[ks & 3], bf, lo0);                                   \
          lo1 = MFMA(a1l1[ks & 3], bf, lo1);                                   \
        }                                                                      \
      }                                                                        \
    }                                                                          \
    /* ---- gate -> GEMM2 B-fragments (registers) ---- */                      \
    halfx8 gh0a, gh0b, gl0a, gl0b, gh1a, gh1b, gl1a, gl1b;                     \
    _Pragma("unroll")                                                          \
    for (int r = 0; r < 16; ++r) {                                             \
      float ha = hi0[r] + lo0[r] * (1.f / 2048.f);                             \
      float hb = hi1[r] + lo1[r] * (1.f / 2048.f);                             \
      ha = fmaxf(ha, -30.f);                                                   \
      hb = fmaxf(hb, -30.f);                                                   \
      float ea = __expf(-ha), eb = __expf(-hb);                                \
      float ga = (1.f - ea) * __builtin_amdgcn_rcpf(1.f + ea * ea);            \
      float gb = (1.f - eb) * __builtin_amdgcn_rcpf(1.f + eb * eb);            \
      half_t ga0 = (half_t)ga;                                                 \
      half_t gb0 = (half_t)gb;                                                 \
      half_t ga1 = (half_t)((ga - (float)ga0) * 2048.f);                       \
      half_t gb1 = (half_t)((gb - (float)gb0) * 2048.f);                       \
      if (r < 8) {                                                             \
        gh0a[r] = ga0; gl0a[r] = ga1; gh1a[r] = gb0; gl1a[r] = gb1;            \
      } else {                                                                 \
        gh0b[r - 8] = ga0; gl0b[r - 8] = ga1;                                  \
        gh1b[r - 8] = gb0; gl1b[r - 8] = gb1;                                  \
      }                                                                        \
    }                                                                          \
    /* ---- GEMM2: skip partial, register operands ---- */                     \
    f32x16 shi{}, slo{};                                                       \
    shi = MFMA(wrHi[0], gh0a, shi);                                            \
    shi = MFMA(wrHi[1], gh0b, shi);                                            \
    shi = MFMA(wrHi[2], gh1a, shi);                                            \
    shi = MFMA(wrHi[3], gh1b, shi);                                            \
    slo = MFMA(wrHi[0], gl0a, slo);                                            \
    slo = MFMA(wrHi[1], gl0b, slo);                                            \
    slo = MFMA(wrHi[2], gl1a, slo);                                            \
    slo = MFMA(wrHi[3], gl1b, slo);                                            \
    slo = MFMA(wrLo[0], gh0a, slo);                                            \
    slo = MFMA(wrLo[1], gh0b, slo);                                            \
    slo = MFMA(wrLo[2], gh1a, slo);                                            \
    slo = MFMA(wrLo[3], gh1b, slo);                                            \
    __syncthreads(); /* zT reads done; overlay with skb */                     \
    {                                                                          \
      float* skb = (float*)sm + mh * 32 * 68;                                  \
      _Pragma("unroll")                                                        \
      for (int r = 0; r < 16; ++r) {                                           \
        int row = (r & 3) + 8 * (r >> 2) + 4 * lhi;                            \
        skb[row * 68 + nh * 32 + l31] = shi[r] + slo[r] * (1.f / 2048.f);      \
      }                                                                        \
    }                                                                          \
    __syncthreads();                                                           \
    /* ---- writeout: resOut = cur(regs) + skb0 + skb1 ---- */                 \
    {                                                                          \
      const float* s0 = (const float*)sm + cth * 68 + twh;                     \
      const float* s1 = s0 + 32 * 68;                                          \
      size_t base = ((size_t)b * 32 + cth) * T_LEN + t0 + twh;                 \
      _Pragma("unroll")                                                        \
      for (int v = 0; v < 8; v += 4) {                                         \
        float4 sa = *(const float4*)(s0 + v);                                  \
        float4 sb = *(const float4*)(s1 + v);                                  \
        float4 o;                                                              \
        o.x = (CV)[v]     + sa.x + sb.x;                                       \
        o.y = (CV)[v + 1] + sa.y + sb.y;                                       \
        o.z = (CV)[v + 2] + sa.z + sb.z;                                       \
        o.w = (CV)[v + 3] + sa.w + sb.w;                                       \
        *(float4*)(resOut + base + v) = o;                                     \
      }                                                                        \
    }                                                                          \
    __syncthreads(); /* skb reads done before next stage overwrites zT */      \
  }

__global__ __launch_bounds__(256, 2) void layer_k(const float* __restrict__ resIn,
                                                  float* __restrict__ resOut,
                                                  const half_t* __restrict__ WaL,
                                                  const half_t* __restrict__ WrL,
                                                  int d) {
  __shared__ __align__(16) char sm[17408];
  int tid = threadIdx.x;
  int wave = tid >> 6, lane = tid & 63;
  int l31 = lane & 31, lhi = lane >> 5;
  int mh = wave & 1, nh = wave >> 1;        // wave owns m-half mh, t-half nh
  int cth = tid >> 3, twh = (tid & 7) * 8;  // staging/writeout thread mapping

  // ---- per-layer weights into regs (persist across 4 tiles) ----
  halfx8 a1h0[4], a1l0[4], a1h1[4], a1l1[4];
  {
    const half_t* wa = WaL + (mh * 64 + l31) * 128 + lhi * 8;
#pragma unroll
    for (int j = 0; j < 4; ++j) {
      a1h0[j] = *(const halfx8*)(wa + j * 16);
      a1l0[j] = *(const halfx8*)(wa + 64 + j * 16);
      a1h1[j] = *(const halfx8*)(wa + 32 * 128 + j * 16);
      a1l1[j] = *(const halfx8*)(wa + 32 * 128 + 64 + j * 16);
    }
  }
  halfx8 wrHi[4], wrLo[4];
  {
    const half_t* wr = WrL + l31 * 256 + mh * 64 + lhi * 8;
#pragma unroll
    for (int q = 0; q < 4; ++q) {
      wrHi[q] = *(const halfx8*)(wr + q * 16);
      wrLo[q] = *(const halfx8*)(wr + 128 + q * 16);
    }
  }

  float cvA[8], pvA[8], cvB[8], pvB[8];
  LOAD_TILE(0, cvA, pvA);

  TILE_BODY(0, cvA, pvA, cvB, pvB, 1)
  TILE_BODY(1, cvB, pvB, cvA, pvA, 1)
  TILE_BODY(2, cvA, pvA, cvB, pvB, 1)
  TILE_BODY(3, cvB, pvB, cvA, pvA, 0)
}

// ---------------- end: relu(resF-res0) -> relu(We1@.) -> We2@. , MFMA split-2 ----------------
__global__ __launch_bounds__(512) void end_k(const float* __restrict__ resF,
                                             const float* __restrict__ res0,
                                             const half_t* __restrict__ We1S,
                                             const half_t* __restrict__ We2S,
                                             float* __restrict__ out) {
  __shared__ __align__(16) char sm[75776];
  const int H2T_OFF = 0, H1F_OFF = 0, H1T_OFF = 66560;
  int tid = threadIdx.x;
  int b = blockIdx.x / NTILE;
  int t0 = (blockIdx.x % NTILE) * TT;

  {
    int c = tid >> 4, tt4 = (tid & 15) * 4;
    size_t base = ((size_t)b * 32 + c) * T_LEN + t0 + tt4;
    float4 f = *(const float4*)(resF + base);
    float4 z = *(const float4*)(res0 + base);
    float* h1 = (float*)(sm + H1F_OFF) + c * 68 + tt4;
    h1[0] = fmaxf(f.x - z.x, 0.f);
    h1[1] = fmaxf(f.y - z.y, 0.f);
    h1[2] = fmaxf(f.z - z.z, 0.f);
    h1[3] = fmaxf(f.w - z.w, 0.f);
  }
  __syncthreads();
  {
    int t = tid & 63, cg2 = tid >> 6;
    const float* h1 = (const float*)(sm + H1F_OFF);
    halfx4 hi, lo;
#pragma unroll
    for (int j = 0; j < 4; ++j) {
      float v = h1[(cg2 * 4 + j) * 68 + t];
      half_t h = (half_t)v;
      hi[j] = h;
      lo[j] = (half_t)((v - (float)h) * 2048.f);
    }
    half_t* h1t = (half_t*)(sm + H1T_OFF) + t * 72;
    *(halfx4*)(h1t + cg2 * 4)      = hi;
    *(halfx4*)(h1t + 32 + cg2 * 4) = lo;
  }
  __syncthreads();

  int wave = tid >> 6, lane = tid & 63;
  int l31 = lane & 31, lhi = lane >> 5;

  f32x16 aHi0{}, aHi1{}, aLo0{}, aLo1{};
  {
    const char* h1t = sm + H1T_OFF;
    const half_t* wp = We1S + (wave * 32 + l31) * 64;
#pragma unroll
    for (int ks = 0; ks < 2; ++ks) {
      halfx8 hiA = *(const halfx8*)(wp + ks * 16 + lhi * 8);
      halfx8 loA = *(const halfx8*)(wp + 32 + ks * 16 + lhi * 8);
      const char* br0 = h1t + l31 * 144;
      const char* br1 = h1t + (32 + l31) * 144;
      halfx8 hiB0 = *(const halfx8*)(br0 + (ks * 16 + lhi * 8) * 2);
      halfx8 loB0 = *(const halfx8*)(br0 + (32 + ks * 16 + lhi * 8) * 2);
      halfx8 hiB1 = *(const halfx8*)(br1 + (ks * 16 + lhi * 8) * 2);
      halfx8 loB1 = *(const halfx8*)(br1 + (32 + ks * 16 + lhi * 8) * 2);
      aHi0 = MFMA(hiA, hiB0, aHi0);
      aLo0 = MFMA(hiA, loB0, aLo0);
      aLo0 = MFMA(loA, hiB0, aLo0);
      aHi1 = MFMA(hiA, hiB1, aHi1);
      aLo1 = MFMA(hiA, loB1, aLo1);
      aLo1 = MFMA(loA, hiB1, aLo1);
    }
  }
  {
#pragma unroll
    for (int n = 0; n < 2; ++n) {
      const f32x16& aH = n ? aHi1 : aHi0;
      const f32x16& aL = n ? aLo1 : aLo0;
      int t = n * 32 + l31;
      half_t* row = (half_t*)(sm + H2T_OFF) + t * 520;
#pragma unroll
      for (int g = 0; g < 4; ++g) {
        halfx4 hi, lo;
#pragma unroll
        for (int j = 0; j < 4; ++j) {
          int r = g * 4 + j;
          float v = aH[r] + aL[r] * (1.f / 2048.f);
          v = fmaxf(v, 0.f);
          half_t h = (half_t)v;
          hi[j] = h;
          lo[j] = (half_t)((v - (float)h) * 2048.f);
        }
        int col = wave * 32 + g * 8 + lhi * 4;
        *(halfx4*)(row + col)       = hi;
        *(halfx4*)(row + 256 + col) = lo;
      }
    }
  }
  __syncthreads();

  f32x16 bHi0{}, bHi1{}, bLo0{}, bLo1{};
  {
    const half_t* wp = We2S + (size_t)(wave * 32 + l31) * 512;
    const char* h2t = sm + H2T_OFF;
#pragma unroll 2
    for (int ks = 0; ks < 16; ++ks) {
      halfx8 hiA = *(const halfx8*)(wp + ks * 16 + lhi * 8);
      halfx8 loA = *(const halfx8*)(wp + 256 + ks * 16 + lhi * 8);
      const char* br0 = h2t + l31 * 1040;
      const char* br1 = h2t + (32 + l31) * 1040;
      halfx8 hiB0 = *(const halfx8*)(br0 + (ks * 16 + lhi * 8) * 2);
      halfx8 loB0 = *(const halfx8*)(br0 + (256 + ks * 16 + lhi * 8) * 2);
      halfx8 hiB1 = *(const halfx8*)(br1 + (ks * 16 + lhi * 8) * 2);
      halfx8 loB1 = *(const halfx8*)(br1 + (256 + ks * 16 + lhi * 8) * 2);
      bHi0 = MFMA(hiA, hiB0, bHi0);
      bLo0 = MFMA(hiA, loB0, bLo0);
      bLo0 = MFMA(loA, hiB0, bLo0);
      bHi1 = MFMA(hiA, hiB1, bHi1);
      bLo1 = MFMA(hiA, loB1, bLo1);
      bLo1 = MFMA(loA, hiB1, bLo1);
    }
  }
  {
#pragma unroll
    for (int n = 0; n < 2; ++n) {
      const f32x16& bH = n ? bHi1 : bHi0;
      const f32x16& bL = n ? bLo1 : bLo0;
      int t = t0 + n * 32 + l31;
#pragma unroll
      for (int r = 0; r < 16; ++r) {
        int o = wave * 32 + (r & 3) + 8 * (r >> 2) + 4 * lhi;
        out[((size_t)b * 256 + o) * T_LEN + t] = bH[r] + bL[r] * (1.f / 2048.f);
      }
    }
  }
}

extern "C" void kernel_launch(void* const* d_in, const int* in_sizes, int n_in,
                              void* d_out, int out_size, void* d_ws, size_t ws_size,
                              hipStream_t stream) {
  const float* x   = (const float*)d_in[0];
  const float* Wst = (const float*)d_in[1];
  const float* Wd  = (const float*)d_in[2];
  const float* Wr  = (const float*)d_in[3];
  const float* We1 = (const float*)d_in[4];
  const float* We2 = (const float*)d_in[5];
  float* out = (float*)d_out;
  float* ws = (float*)d_ws;

  float* resA = ws;                        // start output (skips = resF - resA)
  float* resB = resA + N_RES;
  float* resC = resB + N_RES;
  half_t* WaG  = (half_t*)(resC + N_RES);  // 40*16384
  half_t* WrG  = WaG + 40 * 16384;         // 40*8192
  float*  WsT  = (float*)(WrG + 40 * 8192);
  half_t* We1S = (half_t*)(WsT + 8192);    // 16384
  half_t* We2S = We1S + 16384;             // 131072

  repack_k<<<2560, 256, 0, stream>>>(Wd, Wr, Wst, We1, We2, WaG, WrG, WsT, We1S, We2S);
  start_k<<<NBLK, 256, 0, stream>>>(x, WsT, resA);

  const float* rin = resA;
  for (int l = 0; l < 40; ++l) {
    float* rout = (l & 1) ? resC : resB;
    layer_k<<<LGRID, 256, 0, stream>>>(rin, rout, WaG + l * 16384, WrG + l * 8192,
                                       1 << (l % 10));
    rin = rout;
  }
  end_k<<<NBLK, 512, 0, stream>>>(rin, resA, We1S, We2S, out);
}